// Round 4
// baseline (10761.364 us; speedup 1.0000x reference)
//
#include <hip/hip_runtime.h>
#include <hip/hip_bf16.h>

#define B_   512
#define L_   64
#define D_   16
#define H_   256
#define V_   512
#define STEPS_ 64
#define DT_  0.984375f
#define LOSC 2048.0f          // lo-term scale 2^11
#define LOSC_INV (1.0f/2048.0f)

typedef _Float16 half_t;
typedef __attribute__((ext_vector_type(8))) _Float16 half8;
typedef __attribute__((ext_vector_type(4))) float f32x4;

__device__ __forceinline__ void split16(float x, half_t& hi, half_t& lo) {
    half_t h = (half_t)x;
    hi = h;
    lo = (half_t)((x - (float)h) * LOSC);
}

// ---------------- prep kernels ----------------

// Pack W [N][K] fp32 into MFMA B-fragment order, f16 hi + scaled-lo:
// slot idx = ((g*Kc + c)*64 + l)*8 + j  <-  W[g*16 + (l&15)][c*32 + (l>>4)*8 + j]
__global__ void pack_frag_kernel(const float* __restrict__ src, half_t* __restrict__ hi,
                                 half_t* __restrict__ lo, int Kc, int K, int total) {
    int idx = blockIdx.x * 256 + threadIdx.x;
    if (idx >= total) return;
    int j = idx & 7;
    int l = (idx >> 3) & 63;
    int gc = idx >> 9;
    int c = gc % Kc, g = gc / Kc;
    int n = (g << 4) + (l & 15);
    int k = (c << 5) + ((l >> 4) << 3) + j;
    float w = src[n * K + k];
    half_t h, lw;
    split16(w, h, lw);
    hi[idx] = h;
    lo[idx] = lw;
}

// h0 = tanh(X0 @ W0^T + b0)
__global__ void h0_kernel(const float* __restrict__ coeffs, const float* __restrict__ W0,
                          const float* __restrict__ b0, float* __restrict__ hout) {
    int b = blockIdx.x;
    int hh = threadIdx.x;
    float acc = b0[hh];
    #pragma unroll
    for (int d = 0; d < 16; d++)
        acc += coeffs[b * ((L_ - 1) * 4 * D_) + d] * W0[hh * 16 + d];
    hout[b * H_ + hh] = tanhf(acc);
}

// ---------------- persistent step kernel ----------------

struct NcdeParams {
    const float* coeffs;
    const half_t* W1h; const half_t* W1l; const float* b1; const float* g1; const float* be1;
    const half_t* W2h; const half_t* W2l; const float* b2; const float* g2; const float* be2;
    const half_t* W3h; const half_t* W3l; const float* b3;
    float* hbuf;
    half_t* t1h; half_t* t1l; half_t* t2h; half_t* t2l;
    unsigned* bar;
};

// smem layout (bytes):
//   Ah   @ 0      (32 KB)
//   Al   @ 32768  (32 KB)
//   part @ 65536  (4 KB)
//   mr   @ 69632  (128 B)
//   rrs  @ 69760  (128 B)
//   dxs  @ 69888  (2176 B)   total 72064
#define SMEM_BYTES 72064

// device-scope grid barrier: monotonic counter, all 256 blocks co-resident.
__device__ __forceinline__ void grid_barrier(unsigned* bar, unsigned target) {
    __syncthreads();
    if (threadIdx.x == 0) {
        __threadfence();   // flush this block's phase writes (agent scope)
        __hip_atomic_fetch_add(bar, 1u, __ATOMIC_RELEASE, __HIP_MEMORY_SCOPE_AGENT);
        while (__hip_atomic_load(bar, __ATOMIC_ACQUIRE, __HIP_MEMORY_SCOPE_AGENT) < target)
            __builtin_amdgcn_s_sleep(2);
        __threadfence();   // invalidate stale cached data before next phase reads
    }
    __syncthreads();
}

// Phase 1: t1 = tanh(h @ W1^T + b1) -> packed f16 hi/lo fragments. 128 blocks, 32x64 tile.
__device__ __forceinline__ void phase1(int bx, int by, char* smem, const NcdeParams& P) {
    half_t* Ah = (half_t*)smem;
    half_t* Al = (half_t*)(smem + 32768);
    const int tid = threadIdx.x, w = tid >> 6, l = tid & 63;
    const int row0 = bx * 32, col0 = by * 64;

    {
        int gm = w & 1;
        #pragma unroll
        for (int cc = 0; cc < 2; cc++) {
            int c = ((w >> 1) << 1) + cc;
            const float* src = P.hbuf + (row0 + (gm << 4) + (l & 15)) * H_ + (c << 5) + ((l >> 4) << 3);
            float4 x = *(const float4*)src;
            float4 y = *(const float4*)(src + 4);
            float xx[8] = {x.x, x.y, x.z, x.w, y.x, y.y, y.z, y.w};
            half8 hv, lv;
            #pragma unroll
            for (int j = 0; j < 8; j++) { half_t a, b; split16(xx[j], a, b); hv[j] = a; lv[j] = b; }
            int base = (((gm << 3) + c) * 64 + l) * 8;
            *(half8*)&Ah[base] = hv;
            *(half8*)&Al[base] = lv;
        }
    }
    __syncthreads();

    const int mf = w & 1, nf = w >> 1;
    const int gn = (col0 >> 4) + nf;
    f32x4 acc = {0.f, 0.f, 0.f, 0.f}, accl = {0.f, 0.f, 0.f, 0.f};
    for (int c = 0; c < 8; c++) {
        half8 ah = *(const half8*)&Ah[(((mf << 3) + c) * 64 + l) * 8];
        half8 al = *(const half8*)&Al[(((mf << 3) + c) * 64 + l) * 8];
        half8 bh = *(const half8*)&P.W1h[(((gn << 3) + c) * 64 + l) * 8];
        half8 bl = *(const half8*)&P.W1l[(((gn << 3) + c) * 64 + l) * 8];
        acc  = __builtin_amdgcn_mfma_f32_16x16x32_f16(ah, bh, acc,  0, 0, 0);
        accl = __builtin_amdgcn_mfma_f32_16x16x32_f16(ah, bl, accl, 0, 0, 0);
        accl = __builtin_amdgcn_mfma_f32_16x16x32_f16(al, bh, accl, 0, 0, 0);
    }
    __syncthreads();                       // all waves done reading Ah -> reuse as zs
    float (*zs)[65] = (float(*)[65])smem;
    {
        int colb = (nf << 4) + (l & 15);
        float bb = P.b1[col0 + colb];
        #pragma unroll
        for (int j = 0; j < 4; j++) {
            float v = acc[j] + accl[j] * LOSC_INV + bb;
            zs[(mf << 4) + ((l >> 4) << 2) + j][colb] = tanhf(v);
        }
    }
    __syncthreads();
    if (tid < 256) {
        int p = tid >> 6;              // (gm' 2) x (c' 2)
        int gmp = p & 1, cp = p >> 1;
        half8 hv, lv;
        #pragma unroll
        for (int j = 0; j < 8; j++) {
            float v = zs[(gmp << 4) + (l & 15)][(cp << 5) + ((l >> 4) << 3) + j];
            half_t a, b; split16(v, a, b); hv[j] = a; lv[j] = b;
        }
        int base = ((((row0 >> 4) + gmp) * 16 + (col0 >> 5) + cp) * 64 + l) * 8;
        *(half8*)&P.t1h[base] = hv;
        *(half8*)&P.t1l[base] = lv;
    }
}

// Phase 2: t2 = tanh(LN1(t1) @ W2^T + b2) -> packed fragments. 128 blocks, 32x64 tile.
__device__ __forceinline__ void phase2(int bx, int by, char* smem, const NcdeParams& P) {
    half_t* Ah = (half_t*)smem;
    half_t* Al = (half_t*)(smem + 32768);
    float* part = (float*)(smem + 65536);
    float* mr   = (float*)(smem + 69632);
    float* rrs  = (float*)(smem + 69760);
    const int tid = threadIdx.x, w = tid >> 6, l = tid & 63;
    const int row0 = bx * 32, col0 = by * 64;
    const int gm = w & 1, cbase = (w >> 1) << 2;

    float tv[32];
    {
        float s = 0.f, ss = 0.f;
        #pragma unroll
        for (int cc = 0; cc < 4; cc++) {
            int c = cbase + cc;
            int base = ((((row0 >> 4) + gm) * 16 + c) * 64 + l) * 8;
            half8 hv = *(const half8*)&P.t1h[base];
            half8 lv = *(const half8*)&P.t1l[base];
            #pragma unroll
            for (int j = 0; j < 8; j++) {
                float t = (float)hv[j] + (float)lv[j] * LOSC_INV;
                tv[(cc << 3) + j] = t;
                s += t; ss += t * t;
            }
        }
        part[w * 64 + l] = s;
        part[512 + w * 64 + l] = ss;
    }
    __syncthreads();
    if (tid < 32) {
        int r = tid, rgm = r >> 4;
        float s = 0.f, ss = 0.f;
        #pragma unroll
        for (int wi = 0; wi < 4; wi++) {
            int wv = rgm + (wi << 1);
            #pragma unroll
            for (int u = 0; u < 4; u++) {
                int idx = wv * 64 + (r & 15) + (u << 4);
                s += part[idx]; ss += part[512 + idx];
            }
        }
        float m = s * (1.f / 512.f);
        float var = ss * (1.f / 512.f) - m * m;
        mr[r] = m;
        rrs[r] = rsqrtf(var + 1e-5f);
    }
    __syncthreads();
    {
        int row = (gm << 4) + (l & 15);
        float m = mr[row], rv = rrs[row];
        #pragma unroll
        for (int cc = 0; cc < 4; cc++) {
            int c = cbase + cc;
            half8 hv, lv;
            #pragma unroll
            for (int j = 0; j < 8; j++) {
                int k = (c << 5) + ((l >> 4) << 3) + j;
                float val = (tv[(cc << 3) + j] - m) * rv * P.g1[k] + P.be1[k];
                half_t a, b; split16(val, a, b); hv[j] = a; lv[j] = b;
            }
            int base = (((gm << 4) + c) * 64 + l) * 8;
            *(half8*)&Ah[base] = hv;
            *(half8*)&Al[base] = lv;
        }
    }
    __syncthreads();

    const int mf = w & 1, nf = w >> 1;
    const int gn = (col0 >> 4) + nf;
    f32x4 acc = {0.f, 0.f, 0.f, 0.f}, accl = {0.f, 0.f, 0.f, 0.f};
    for (int c = 0; c < 16; c++) {
        half8 ah = *(const half8*)&Ah[(((mf << 4) + c) * 64 + l) * 8];
        half8 al = *(const half8*)&Al[(((mf << 4) + c) * 64 + l) * 8];
        half8 bh = *(const half8*)&P.W2h[(((gn << 4) + c) * 64 + l) * 8];
        half8 bl = *(const half8*)&P.W2l[(((gn << 4) + c) * 64 + l) * 8];
        acc  = __builtin_amdgcn_mfma_f32_16x16x32_f16(ah, bh, acc,  0, 0, 0);
        accl = __builtin_amdgcn_mfma_f32_16x16x32_f16(ah, bl, accl, 0, 0, 0);
        accl = __builtin_amdgcn_mfma_f32_16x16x32_f16(al, bh, accl, 0, 0, 0);
    }
    __syncthreads();
    float (*zs)[65] = (float(*)[65])smem;
    {
        int colb = (nf << 4) + (l & 15);
        float bb = P.b2[col0 + colb];
        #pragma unroll
        for (int j = 0; j < 4; j++) {
            float v = acc[j] + accl[j] * LOSC_INV + bb;
            zs[(mf << 4) + ((l >> 4) << 2) + j][colb] = tanhf(v);
        }
    }
    __syncthreads();
    if (tid < 256) {
        int p = tid >> 6;
        int gmp = p & 1, cp = p >> 1;
        half8 hv, lv;
        #pragma unroll
        for (int j = 0; j < 8; j++) {
            float v = zs[(gmp << 4) + (l & 15)][(cp << 5) + ((l >> 4) << 3) + j];
            half_t a, b; split16(v, a, b); hv[j] = a; lv[j] = b;
        }
        int base = ((((row0 >> 4) + gmp) * 16 + (col0 >> 5) + cp) * 64 + l) * 8;
        *(half8*)&P.t2h[base] = hv;
        *(half8*)&P.t2l[base] = lv;
    }
}

// Phase 3: vf = LN2(t2) @ W3^T + b3; h += dt*(vf . dX). 256 blocks, 32 rows x 256 cols.
__device__ __forceinline__ void phase3(int bx, int by, char* smem, const NcdeParams& P,
                                       int ii, float frac) {
    half_t* Ah = (half_t*)smem;
    half_t* Al = (half_t*)(smem + 32768);
    float* part = (float*)(smem + 65536);
    float* mr   = (float*)(smem + 69632);
    float* rrs  = (float*)(smem + 69760);
    float (*dxs)[17] = (float(*)[17])(smem + 69888);
    const int tid = threadIdx.x, w = tid >> 6, l = tid & 63;
    const int row0 = bx * 32, col0 = by * 256;
    const int gm = w & 1, cbase = (w >> 1) << 2;

    {
        int r = tid >> 4, d = tid & 15;
        int b = row0 + r;
        int base = (b * (L_ - 1) + ii) * 64 + d;
        float c1 = P.coeffs[base + 16], c2 = P.coeffs[base + 32], c3 = P.coeffs[base + 48];
        dxs[r][d] = c1 + 2.0f * frac * c2 + 3.0f * (frac * frac) * c3;
    }

    float tv[32];
    {
        float s = 0.f, ss = 0.f;
        #pragma unroll
        for (int cc = 0; cc < 4; cc++) {
            int c = cbase + cc;
            int base = ((((row0 >> 4) + gm) * 16 + c) * 64 + l) * 8;
            half8 hv = *(const half8*)&P.t2h[base];
            half8 lv = *(const half8*)&P.t2l[base];
            #pragma unroll
            for (int j = 0; j < 8; j++) {
                float t = (float)hv[j] + (float)lv[j] * LOSC_INV;
                tv[(cc << 3) + j] = t;
                s += t; ss += t * t;
            }
        }
        part[w * 64 + l] = s;
        part[512 + w * 64 + l] = ss;
    }
    __syncthreads();
    if (tid < 32) {
        int r = tid, rgm = r >> 4;
        float s = 0.f, ss = 0.f;
        #pragma unroll
        for (int wi = 0; wi < 4; wi++) {
            int wv = rgm + (wi << 1);
            #pragma unroll
            for (int u = 0; u < 4; u++) {
                int idx = wv * 64 + (r & 15) + (u << 4);
                s += part[idx]; ss += part[512 + idx];
            }
        }
        float m = s * (1.f / 512.f);
        float var = ss * (1.f / 512.f) - m * m;
        mr[r] = m;
        rrs[r] = rsqrtf(var + 1e-5f);
    }
    __syncthreads();
    {
        int row = (gm << 4) + (l & 15);
        float m = mr[row], rv = rrs[row];
        #pragma unroll
        for (int cc = 0; cc < 4; cc++) {
            int c = cbase + cc;
            half8 hv, lv;
            #pragma unroll
            for (int j = 0; j < 8; j++) {
                int k = (c << 5) + ((l >> 4) << 3) + j;
                float val = (tv[(cc << 3) + j] - m) * rv * P.g2[k] + P.be2[k];
                half_t a, b; split16(val, a, b); hv[j] = a; lv[j] = b;
            }
            int base = (((gm << 4) + c) * 64 + l) * 8;
            *(half8*)&Ah[base] = hv;
            *(half8*)&Al[base] = lv;
        }
    }
    __syncthreads();

    f32x4 acc[2][2], accl[2][2];
    #pragma unroll
    for (int a = 0; a < 2; a++)
        #pragma unroll
        for (int b = 0; b < 2; b++) { acc[a][b] = (f32x4){0.f,0.f,0.f,0.f}; accl[a][b] = (f32x4){0.f,0.f,0.f,0.f}; }

    for (int c = 0; c < 16; c++) {
        half8 ah0 = *(const half8*)&Ah[((c) * 64 + l) * 8];
        half8 al0 = *(const half8*)&Al[((c) * 64 + l) * 8];
        half8 ah1 = *(const half8*)&Ah[((16 + c) * 64 + l) * 8];
        half8 al1 = *(const half8*)&Al[((16 + c) * 64 + l) * 8];
        #pragma unroll
        for (int nfi = 0; nfi < 2; nfi++) {
            int gn = (col0 >> 4) + (w << 1) + nfi;
            half8 bh = *(const half8*)&P.W3h[(((gn << 4) + c) * 64 + l) * 8];
            half8 bl = *(const half8*)&P.W3l[(((gn << 4) + c) * 64 + l) * 8];
            acc[0][nfi]  = __builtin_amdgcn_mfma_f32_16x16x32_f16(ah0, bh, acc[0][nfi],  0, 0, 0);
            accl[0][nfi] = __builtin_amdgcn_mfma_f32_16x16x32_f16(ah0, bl, accl[0][nfi], 0, 0, 0);
            accl[0][nfi] = __builtin_amdgcn_mfma_f32_16x16x32_f16(al0, bh, accl[0][nfi], 0, 0, 0);
            acc[1][nfi]  = __builtin_amdgcn_mfma_f32_16x16x32_f16(ah1, bh, acc[1][nfi],  0, 0, 0);
            accl[1][nfi] = __builtin_amdgcn_mfma_f32_16x16x32_f16(ah1, bl, accl[1][nfi], 0, 0, 0);
            accl[1][nfi] = __builtin_amdgcn_mfma_f32_16x16x32_f16(al1, bh, accl[1][nfi], 0, 0, 0);
        }
    }

    const int d = l & 15;
    #pragma unroll
    for (int nfi = 0; nfi < 2; nfi++) {
        int hh = (col0 >> 4) + (w << 1) + nfi;
        float b3v = P.b3[(hh << 4) + d];
        #pragma unroll
        for (int mf = 0; mf < 2; mf++) {
            #pragma unroll
            for (int j = 0; j < 4; j++) {
                int rl = (mf << 4) + ((l >> 4) << 2) + j;
                float v = acc[mf][nfi][j] + accl[mf][nfi][j] * LOSC_INV + b3v;
                float s = v * dxs[rl][d];
                s += __shfl_xor(s, 1);
                s += __shfl_xor(s, 2);
                s += __shfl_xor(s, 4);
                s += __shfl_xor(s, 8);
                if (d == 0) P.hbuf[(row0 + rl) * H_ + hh] += s * DT_;
            }
        }
    }
}

__global__ __launch_bounds__(512) void ncde_persistent(NcdeParams P) {
    __shared__ __align__(16) char smem[SMEM_BYTES];
    const int bid = blockIdx.x;
    unsigned epoch = 0;
    for (int s = 0; s < STEPS_; s++) {
        float t = (float)s * 0.984375f;      // exact in fp32
        int ii = (int)t;
        if (ii > L_ - 2) ii = L_ - 2;
        float frac = t - (float)ii;

        if (bid < 128) phase1(bid & 15, bid >> 4, smem, P);
        grid_barrier(P.bar, ++epoch * 256u);

        if (bid < 128) phase2(bid & 15, bid >> 4, smem, P);
        grid_barrier(P.bar, ++epoch * 256u);

        // XCD-swizzled mapping: 16 row-tiles sharing a W3 col-slice land on one XCD
        {
            int x = bid & 7, k = bid >> 3;
            phase3(k >> 1, 2 * x + (k & 1), smem, P, ii, frac);
        }
        grid_barrier(P.bar, ++epoch * 256u);
    }
}

// ---------------- launch ----------------

extern "C" void kernel_launch(void* const* d_in, const int* in_sizes, int n_in,
                              void* d_out, int out_size, void* d_ws, size_t ws_size,
                              hipStream_t stream) {
    const float* coeffs = (const float*)d_in[0];
    const float* W0  = (const float*)d_in[1];
    const float* b0  = (const float*)d_in[2];
    const float* W1  = (const float*)d_in[3];
    const float* b1  = (const float*)d_in[4];
    const float* g1  = (const float*)d_in[5];
    const float* be1 = (const float*)d_in[6];
    const float* W2  = (const float*)d_in[7];
    const float* b2  = (const float*)d_in[8];
    const float* g2  = (const float*)d_in[9];
    const float* be2 = (const float*)d_in[10];
    const float* W3  = (const float*)d_in[11];
    const float* b3  = (const float*)d_in[12];

    char* w = (char*)d_ws;
    float*  hbuf = (float*)(w);                       // 512 KB
    half_t* t1h  = (half_t*)(w + 512 * 1024);         // 512 KB
    half_t* t1l  = (half_t*)(w + 1024 * 1024);        // 512 KB
    half_t* t2h  = (half_t*)(w + 1536 * 1024);        // 512 KB
    half_t* t2l  = (half_t*)(w + 2048 * 1024);        // 512 KB
    half_t* W1h  = (half_t*)(w + 2560 * 1024);        // 256 KB
    half_t* W1l  = (half_t*)(w + 2816 * 1024);        // 256 KB
    half_t* W2h  = (half_t*)(w + 3072 * 1024);        // 512 KB
    half_t* W2l  = (half_t*)(w + 3584 * 1024);        // 512 KB
    half_t* W3h  = (half_t*)(w + 4096 * 1024);        // 4 MB
    half_t* W3l  = (half_t*)(w + 8192 * 1024);        // 4 MB
    unsigned* bar = (unsigned*)(w + 12288 * 1024);    // 64 B

    hipMemsetAsync(bar, 0, 64, stream);
    pack_frag_kernel<<<512, 256, 0, stream>>>(W1, W1h, W1l, 8, H_, V_ * H_);
    pack_frag_kernel<<<1024, 256, 0, stream>>>(W2, W2h, W2l, 16, V_, V_ * V_);
    pack_frag_kernel<<<8192, 256, 0, stream>>>(W3, W3h, W3l, 16, V_, (H_ * D_) * V_);
    h0_kernel<<<B_, H_, 0, stream>>>(coeffs, W0, b0, hbuf);

    NcdeParams prm;
    prm.coeffs = coeffs;
    prm.W1h = W1h; prm.W1l = W1l; prm.b1 = b1; prm.g1 = g1; prm.be1 = be1;
    prm.W2h = W2h; prm.W2l = W2l; prm.b2 = b2; prm.g2 = g2; prm.be2 = be2;
    prm.W3h = W3h; prm.W3l = W3l; prm.b3 = b3;
    prm.hbuf = hbuf;
    prm.t1h = t1h; prm.t1l = t1l; prm.t2h = t2h; prm.t2l = t2l;
    prm.bar = bar;

    ncde_persistent<<<256, 512, 0, stream>>>(prm);

    hipMemcpyAsync(d_out, hbuf, (size_t)B_ * H_ * sizeof(float),
                   hipMemcpyDeviceToDevice, stream);
}

// Round 5
// 5191.156 us; speedup vs baseline: 2.0730x; 2.0730x over previous
//
#include <hip/hip_runtime.h>
#include <hip/hip_bf16.h>

#define B_   512
#define L_   64
#define D_   16
#define H_   256
#define V_   512
#define STEPS_ 64
#define DT_  0.984375f
#define LOSC 2048.0f          // lo-term scale 2^11
#define LOSC_INV (1.0f/2048.0f)

typedef _Float16 half_t;
typedef __attribute__((ext_vector_type(8))) _Float16 half8;
typedef __attribute__((ext_vector_type(4))) float f32x4;
typedef unsigned long long u64;

__device__ __forceinline__ void split16(float x, half_t& hi, half_t& lo) {
    half_t h = (half_t)x;
    hi = h;
    lo = (half_t)((x - (float)h) * LOSC);
}

// ---- cache-bypassing (sc0 sc1) accessors: coherent across XCDs with NO fences ----
__device__ __forceinline__ u64 ld_byp_u64(const void* p) {
    return __hip_atomic_load((const u64*)p, __ATOMIC_RELAXED, __HIP_MEMORY_SCOPE_SYSTEM);
}
__device__ __forceinline__ void st_byp_u64(void* p, u64 v) {
    __hip_atomic_store((u64*)p, v, __ATOMIC_RELAXED, __HIP_MEMORY_SCOPE_SYSTEM);
}
__device__ __forceinline__ half8 ld_frag_byp(const half_t* p) {
    u64 t[2];
    t[0] = ld_byp_u64(p);
    t[1] = ld_byp_u64((const char*)p + 8);
    return *(half8*)t;
}
__device__ __forceinline__ void st_frag_byp(half_t* p, half8 v) {
    u64 t[2];
    *(half8*)t = v;
    st_byp_u64(p, t[0]);
    st_byp_u64((char*)p + 8, t[1]);
}
__device__ __forceinline__ float ld_byp_f32(const float* p) {
    return __hip_atomic_load(p, __ATOMIC_RELAXED, __HIP_MEMORY_SCOPE_SYSTEM);
}
__device__ __forceinline__ void st_byp_f32(float* p, float v) {
    __hip_atomic_store(p, v, __ATOMIC_RELAXED, __HIP_MEMORY_SCOPE_SYSTEM);
}

// ---------------- prep kernels ----------------

// Pack W [N][K] fp32 into MFMA B-fragment order, f16 hi + scaled-lo:
// slot idx = ((g*Kc + c)*64 + l)*8 + j  <-  W[g*16 + (l&15)][c*32 + (l>>4)*8 + j]
__global__ void pack_frag_kernel(const float* __restrict__ src, half_t* __restrict__ hi,
                                 half_t* __restrict__ lo, int Kc, int K, int total) {
    int idx = blockIdx.x * 256 + threadIdx.x;
    if (idx >= total) return;
    int j = idx & 7;
    int l = (idx >> 3) & 63;
    int gc = idx >> 9;
    int c = gc % Kc, g = gc / Kc;
    int n = (g << 4) + (l & 15);
    int k = (c << 5) + ((l >> 4) << 3) + j;
    float w = src[n * K + k];
    half_t h, lw;
    split16(w, h, lw);
    hi[idx] = h;
    lo[idx] = lw;
}

// h0 = tanh(X0 @ W0^T + b0)  (bypass store so the persistent kernel's byp loads see it)
__global__ void h0_kernel(const float* __restrict__ coeffs, const float* __restrict__ W0,
                          const float* __restrict__ b0, float* __restrict__ hout) {
    int b = blockIdx.x;
    int hh = threadIdx.x;
    float acc = b0[hh];
    #pragma unroll
    for (int d = 0; d < 16; d++)
        acc += coeffs[b * ((L_ - 1) * 4 * D_) + d] * W0[hh * 16 + d];
    st_byp_f32(&hout[b * H_ + hh], tanhf(acc));
}

// ---------------- persistent step kernel ----------------

struct NcdeParams {
    const float* coeffs;
    const half_t* W1h; const half_t* W1l; const float* b1; const float* g1; const float* be1;
    const half_t* W2h; const half_t* W2l; const float* b2; const float* g2; const float* be2;
    const half_t* W3h; const half_t* W3l; const float* b3;
    float* hbuf;
    half_t* t1h; half_t* t1l; half_t* t2h; half_t* t2l;
    unsigned* bar;
};

// smem layout (bytes):
//   Ah   @ 0      (32 KB)
//   Al   @ 32768  (32 KB)
//   part @ 65536  (4 KB)
//   mr   @ 69632  (128 B)
//   rrs  @ 69760  (128 B)
//   dxs  @ 69888  (2176 B)   total 72064
#define SMEM_BYTES 72064

// Grid barrier WITHOUT cache maintenance: all inter-phase data moves via sc0sc1
// bypass ops (acked at the coherence point before __syncthreads lets any wave pass),
// so the only coherent object is the counter itself (SYSTEM-scope atomics).
__device__ __forceinline__ void grid_barrier(unsigned* bar, unsigned target) {
    __syncthreads();   // drains each wave's vmcnt -> all byp stores globally visible
    if (threadIdx.x == 0) {
        __hip_atomic_fetch_add(bar, 1u, __ATOMIC_RELAXED, __HIP_MEMORY_SCOPE_SYSTEM);
        while (__hip_atomic_load(bar, __ATOMIC_RELAXED, __HIP_MEMORY_SCOPE_SYSTEM) < target)
            __builtin_amdgcn_s_sleep(2);
    }
    __syncthreads();
}

// Phase 1: t1 = tanh(h @ W1^T + b1) -> packed f16 hi/lo fragments. 128 blocks, 32x64 tile.
__device__ __forceinline__ void phase1(int bx, int by, char* smem, const NcdeParams& P) {
    half_t* Ah = (half_t*)smem;
    half_t* Al = (half_t*)(smem + 32768);
    const int tid = threadIdx.x, w = tid >> 6, l = tid & 63;
    const int row0 = bx * 32, col0 = by * 64;

    {
        int gm = w & 1;
        #pragma unroll
        for (int cc = 0; cc < 2; cc++) {
            int c = ((w >> 1) << 1) + cc;
            const float* src = P.hbuf + (row0 + (gm << 4) + (l & 15)) * H_ + (c << 5) + ((l >> 4) << 3);
            u64 q[4];
            q[0] = ld_byp_u64(src);
            q[1] = ld_byp_u64(src + 2);
            q[2] = ld_byp_u64(src + 4);
            q[3] = ld_byp_u64(src + 6);
            const float* xx = (const float*)q;
            half8 hv, lv;
            #pragma unroll
            for (int j = 0; j < 8; j++) { half_t a, b; split16(xx[j], a, b); hv[j] = a; lv[j] = b; }
            int base = (((gm << 3) + c) * 64 + l) * 8;
            *(half8*)&Ah[base] = hv;
            *(half8*)&Al[base] = lv;
        }
    }
    __syncthreads();

    const int mf = w & 1, nf = w >> 1;
    const int gn = (col0 >> 4) + nf;
    f32x4 acc = {0.f, 0.f, 0.f, 0.f}, accl = {0.f, 0.f, 0.f, 0.f};
    for (int c = 0; c < 8; c++) {
        half8 ah = *(const half8*)&Ah[(((mf << 3) + c) * 64 + l) * 8];
        half8 al = *(const half8*)&Al[(((mf << 3) + c) * 64 + l) * 8];
        half8 bh = *(const half8*)&P.W1h[(((gn << 3) + c) * 64 + l) * 8];
        half8 bl = *(const half8*)&P.W1l[(((gn << 3) + c) * 64 + l) * 8];
        acc  = __builtin_amdgcn_mfma_f32_16x16x32_f16(ah, bh, acc,  0, 0, 0);
        accl = __builtin_amdgcn_mfma_f32_16x16x32_f16(ah, bl, accl, 0, 0, 0);
        accl = __builtin_amdgcn_mfma_f32_16x16x32_f16(al, bh, accl, 0, 0, 0);
    }
    __syncthreads();                       // all waves done reading Ah -> reuse as zs
    float (*zs)[65] = (float(*)[65])smem;
    {
        int colb = (nf << 4) + (l & 15);
        float bb = P.b1[col0 + colb];
        #pragma unroll
        for (int j = 0; j < 4; j++) {
            float v = acc[j] + accl[j] * LOSC_INV + bb;
            zs[(mf << 4) + ((l >> 4) << 2) + j][colb] = tanhf(v);
        }
    }
    __syncthreads();
    if (tid < 256) {
        int p = tid >> 6;              // (gm' 2) x (c' 2)
        int gmp = p & 1, cp = p >> 1;
        half8 hv, lv;
        #pragma unroll
        for (int j = 0; j < 8; j++) {
            float v = zs[(gmp << 4) + (l & 15)][(cp << 5) + ((l >> 4) << 3) + j];
            half_t a, b; split16(v, a, b); hv[j] = a; lv[j] = b;
        }
        int base = ((((row0 >> 4) + gmp) * 16 + (col0 >> 5) + cp) * 64 + l) * 8;
        st_frag_byp(&P.t1h[base], hv);
        st_frag_byp(&P.t1l[base], lv);
    }
}

// Phase 2: t2 = tanh(LN1(t1) @ W2^T + b2) -> packed fragments. 128 blocks, 32x64 tile.
__device__ __forceinline__ void phase2(int bx, int by, char* smem, const NcdeParams& P) {
    half_t* Ah = (half_t*)smem;
    half_t* Al = (half_t*)(smem + 32768);
    float* part = (float*)(smem + 65536);
    float* mr   = (float*)(smem + 69632);
    float* rrs  = (float*)(smem + 69760);
    const int tid = threadIdx.x, w = tid >> 6, l = tid & 63;
    const int row0 = bx * 32, col0 = by * 64;
    const int gm = w & 1, cbase = (w >> 1) << 2;

    float tv[32];
    {
        float s = 0.f, ss = 0.f;
        #pragma unroll
        for (int cc = 0; cc < 4; cc++) {
            int c = cbase + cc;
            int base = ((((row0 >> 4) + gm) * 16 + c) * 64 + l) * 8;
            half8 hv = ld_frag_byp(&P.t1h[base]);
            half8 lv = ld_frag_byp(&P.t1l[base]);
            #pragma unroll
            for (int j = 0; j < 8; j++) {
                float t = (float)hv[j] + (float)lv[j] * LOSC_INV;
                tv[(cc << 3) + j] = t;
                s += t; ss += t * t;
            }
        }
        part[w * 64 + l] = s;
        part[512 + w * 64 + l] = ss;
    }
    __syncthreads();
    if (tid < 32) {
        int r = tid, rgm = r >> 4;
        float s = 0.f, ss = 0.f;
        #pragma unroll
        for (int wi = 0; wi < 4; wi++) {
            int wv = rgm + (wi << 1);
            #pragma unroll
            for (int u = 0; u < 4; u++) {
                int idx = wv * 64 + (r & 15) + (u << 4);
                s += part[idx]; ss += part[512 + idx];
            }
        }
        float m = s * (1.f / 512.f);
        float var = ss * (1.f / 512.f) - m * m;
        mr[r] = m;
        rrs[r] = rsqrtf(var + 1e-5f);
    }
    __syncthreads();
    {
        int row = (gm << 4) + (l & 15);
        float m = mr[row], rv = rrs[row];
        #pragma unroll
        for (int cc = 0; cc < 4; cc++) {
            int c = cbase + cc;
            half8 hv, lv;
            #pragma unroll
            for (int j = 0; j < 8; j++) {
                int k = (c << 5) + ((l >> 4) << 3) + j;
                float val = (tv[(cc << 3) + j] - m) * rv * P.g1[k] + P.be1[k];
                half_t a, b; split16(val, a, b); hv[j] = a; lv[j] = b;
            }
            int base = (((gm << 4) + c) * 64 + l) * 8;
            *(half8*)&Ah[base] = hv;
            *(half8*)&Al[base] = lv;
        }
    }
    __syncthreads();

    const int mf = w & 1, nf = w >> 1;
    const int gn = (col0 >> 4) + nf;
    f32x4 acc = {0.f, 0.f, 0.f, 0.f}, accl = {0.f, 0.f, 0.f, 0.f};
    for (int c = 0; c < 16; c++) {
        half8 ah = *(const half8*)&Ah[(((mf << 4) + c) * 64 + l) * 8];
        half8 al = *(const half8*)&Al[(((mf << 4) + c) * 64 + l) * 8];
        half8 bh = *(const half8*)&P.W2h[(((gn << 4) + c) * 64 + l) * 8];
        half8 bl = *(const half8*)&P.W2l[(((gn << 4) + c) * 64 + l) * 8];
        acc  = __builtin_amdgcn_mfma_f32_16x16x32_f16(ah, bh, acc,  0, 0, 0);
        accl = __builtin_amdgcn_mfma_f32_16x16x32_f16(ah, bl, accl, 0, 0, 0);
        accl = __builtin_amdgcn_mfma_f32_16x16x32_f16(al, bh, accl, 0, 0, 0);
    }
    __syncthreads();
    float (*zs)[65] = (float(*)[65])smem;
    {
        int colb = (nf << 4) + (l & 15);
        float bb = P.b2[col0 + colb];
        #pragma unroll
        for (int j = 0; j < 4; j++) {
            float v = acc[j] + accl[j] * LOSC_INV + bb;
            zs[(mf << 4) + ((l >> 4) << 2) + j][colb] = tanhf(v);
        }
    }
    __syncthreads();
    if (tid < 256) {
        int p = tid >> 6;
        int gmp = p & 1, cp = p >> 1;
        half8 hv, lv;
        #pragma unroll
        for (int j = 0; j < 8; j++) {
            float v = zs[(gmp << 4) + (l & 15)][(cp << 5) + ((l >> 4) << 3) + j];
            half_t a, b; split16(v, a, b); hv[j] = a; lv[j] = b;
        }
        int base = ((((row0 >> 4) + gmp) * 16 + (col0 >> 5) + cp) * 64 + l) * 8;
        st_frag_byp(&P.t2h[base], hv);
        st_frag_byp(&P.t2l[base], lv);
    }
}

// Phase 3: vf = LN2(t2) @ W3^T + b3; h += dt*(vf . dX). 256 blocks, 32 rows x 256 cols.
__device__ __forceinline__ void phase3(int bx, int by, char* smem, const NcdeParams& P,
                                       int ii, float frac) {
    half_t* Ah = (half_t*)smem;
    half_t* Al = (half_t*)(smem + 32768);
    float* part = (float*)(smem + 65536);
    float* mr   = (float*)(smem + 69632);
    float* rrs  = (float*)(smem + 69760);
    float (*dxs)[17] = (float(*)[17])(smem + 69888);
    const int tid = threadIdx.x, w = tid >> 6, l = tid & 63;
    const int row0 = bx * 32, col0 = by * 256;
    const int gm = w & 1, cbase = (w >> 1) << 2;

    {
        int r = tid >> 4, d = tid & 15;
        int b = row0 + r;
        int base = (b * (L_ - 1) + ii) * 64 + d;
        float c1 = P.coeffs[base + 16], c2 = P.coeffs[base + 32], c3 = P.coeffs[base + 48];
        dxs[r][d] = c1 + 2.0f * frac * c2 + 3.0f * (frac * frac) * c3;
    }

    float tv[32];
    {
        float s = 0.f, ss = 0.f;
        #pragma unroll
        for (int cc = 0; cc < 4; cc++) {
            int c = cbase + cc;
            int base = ((((row0 >> 4) + gm) * 16 + c) * 64 + l) * 8;
            half8 hv = ld_frag_byp(&P.t2h[base]);
            half8 lv = ld_frag_byp(&P.t2l[base]);
            #pragma unroll
            for (int j = 0; j < 8; j++) {
                float t = (float)hv[j] + (float)lv[j] * LOSC_INV;
                tv[(cc << 3) + j] = t;
                s += t; ss += t * t;
            }
        }
        part[w * 64 + l] = s;
        part[512 + w * 64 + l] = ss;
    }
    __syncthreads();
    if (tid < 32) {
        int r = tid, rgm = r >> 4;
        float s = 0.f, ss = 0.f;
        #pragma unroll
        for (int wi = 0; wi < 4; wi++) {
            int wv = rgm + (wi << 1);
            #pragma unroll
            for (int u = 0; u < 4; u++) {
                int idx = wv * 64 + (r & 15) + (u << 4);
                s += part[idx]; ss += part[512 + idx];
            }
        }
        float m = s * (1.f / 512.f);
        float var = ss * (1.f / 512.f) - m * m;
        mr[r] = m;
        rrs[r] = rsqrtf(var + 1e-5f);
    }
    __syncthreads();
    {
        int row = (gm << 4) + (l & 15);
        float m = mr[row], rv = rrs[row];
        #pragma unroll
        for (int cc = 0; cc < 4; cc++) {
            int c = cbase + cc;
            half8 hv, lv;
            #pragma unroll
            for (int j = 0; j < 8; j++) {
                int k = (c << 5) + ((l >> 4) << 3) + j;
                float val = (tv[(cc << 3) + j] - m) * rv * P.g2[k] + P.be2[k];
                half_t a, b; split16(val, a, b); hv[j] = a; lv[j] = b;
            }
            int base = (((gm << 4) + c) * 64 + l) * 8;
            *(half8*)&Ah[base] = hv;
            *(half8*)&Al[base] = lv;
        }
    }
    __syncthreads();

    f32x4 acc[2][2], accl[2][2];
    #pragma unroll
    for (int a = 0; a < 2; a++)
        #pragma unroll
        for (int b = 0; b < 2; b++) { acc[a][b] = (f32x4){0.f,0.f,0.f,0.f}; accl[a][b] = (f32x4){0.f,0.f,0.f,0.f}; }

    for (int c = 0; c < 16; c++) {
        half8 ah0 = *(const half8*)&Ah[((c) * 64 + l) * 8];
        half8 al0 = *(const half8*)&Al[((c) * 64 + l) * 8];
        half8 ah1 = *(const half8*)&Ah[((16 + c) * 64 + l) * 8];
        half8 al1 = *(const half8*)&Al[((16 + c) * 64 + l) * 8];
        #pragma unroll
        for (int nfi = 0; nfi < 2; nfi++) {
            int gn = (col0 >> 4) + (w << 1) + nfi;
            half8 bh = *(const half8*)&P.W3h[(((gn << 4) + c) * 64 + l) * 8];
            half8 bl = *(const half8*)&P.W3l[(((gn << 4) + c) * 64 + l) * 8];
            acc[0][nfi]  = __builtin_amdgcn_mfma_f32_16x16x32_f16(ah0, bh, acc[0][nfi],  0, 0, 0);
            accl[0][nfi] = __builtin_amdgcn_mfma_f32_16x16x32_f16(ah0, bl, accl[0][nfi], 0, 0, 0);
            accl[0][nfi] = __builtin_amdgcn_mfma_f32_16x16x32_f16(al0, bh, accl[0][nfi], 0, 0, 0);
            acc[1][nfi]  = __builtin_amdgcn_mfma_f32_16x16x32_f16(ah1, bh, acc[1][nfi],  0, 0, 0);
            accl[1][nfi] = __builtin_amdgcn_mfma_f32_16x16x32_f16(ah1, bl, accl[1][nfi], 0, 0, 0);
            accl[1][nfi] = __builtin_amdgcn_mfma_f32_16x16x32_f16(al1, bh, accl[1][nfi], 0, 0, 0);
        }
    }

    const int d = l & 15;
    #pragma unroll
    for (int nfi = 0; nfi < 2; nfi++) {
        int hh = (col0 >> 4) + (w << 1) + nfi;
        float b3v = P.b3[(hh << 4) + d];
        #pragma unroll
        for (int mf = 0; mf < 2; mf++) {
            #pragma unroll
            for (int j = 0; j < 4; j++) {
                int rl = (mf << 4) + ((l >> 4) << 2) + j;
                float v = acc[mf][nfi][j] + accl[mf][nfi][j] * LOSC_INV + b3v;
                float s = v * dxs[rl][d];
                s += __shfl_xor(s, 1);
                s += __shfl_xor(s, 2);
                s += __shfl_xor(s, 4);
                s += __shfl_xor(s, 8);
                if (d == 0) {
                    float* hp = &P.hbuf[(row0 + rl) * H_ + hh];
                    st_byp_f32(hp, ld_byp_f32(hp) + s * DT_);
                }
            }
        }
    }
}

__global__ __launch_bounds__(512) void ncde_persistent(NcdeParams P) {
    __shared__ __align__(16) char smem[SMEM_BYTES];
    const int bid = blockIdx.x;
    unsigned epoch = 0;
    for (int s = 0; s < STEPS_; s++) {
        float t = (float)s * 0.984375f;      // exact in fp32
        int ii = (int)t;
        if (ii > L_ - 2) ii = L_ - 2;
        float frac = t - (float)ii;

        if (bid < 128) phase1(bid & 15, bid >> 4, smem, P);
        grid_barrier(P.bar, ++epoch * 256u);

        if (bid < 128) phase2(bid & 15, bid >> 4, smem, P);
        grid_barrier(P.bar, ++epoch * 256u);

        // XCD-swizzled mapping: 16 row-tiles sharing a W3 col-slice land on one XCD
        {
            int x = bid & 7, k = bid >> 3;
            phase3(k >> 1, 2 * x + (k & 1), smem, P, ii, frac);
        }
        grid_barrier(P.bar, ++epoch * 256u);
    }
}

// ---------------- launch ----------------

extern "C" void kernel_launch(void* const* d_in, const int* in_sizes, int n_in,
                              void* d_out, int out_size, void* d_ws, size_t ws_size,
                              hipStream_t stream) {
    const float* coeffs = (const float*)d_in[0];
    const float* W0  = (const float*)d_in[1];
    const float* b0  = (const float*)d_in[2];
    const float* W1  = (const float*)d_in[3];
    const float* b1  = (const float*)d_in[4];
    const float* g1  = (const float*)d_in[5];
    const float* be1 = (const float*)d_in[6];
    const float* W2  = (const float*)d_in[7];
    const float* b2  = (const float*)d_in[8];
    const float* g2  = (const float*)d_in[9];
    const float* be2 = (const float*)d_in[10];
    const float* W3  = (const float*)d_in[11];
    const float* b3  = (const float*)d_in[12];

    char* w = (char*)d_ws;
    float*  hbuf = (float*)(w);                       // 512 KB
    half_t* t1h  = (half_t*)(w + 512 * 1024);         // 512 KB
    half_t* t1l  = (half_t*)(w + 1024 * 1024);        // 512 KB
    half_t* t2h  = (half_t*)(w + 1536 * 1024);        // 512 KB
    half_t* t2l  = (half_t*)(w + 2048 * 1024);        // 512 KB
    half_t* W1h  = (half_t*)(w + 2560 * 1024);        // 256 KB
    half_t* W1l  = (half_t*)(w + 2816 * 1024);        // 256 KB
    half_t* W2h  = (half_t*)(w + 3072 * 1024);        // 512 KB
    half_t* W2l  = (half_t*)(w + 3584 * 1024);        // 512 KB
    half_t* W3h  = (half_t*)(w + 4096 * 1024);        // 4 MB
    half_t* W3l  = (half_t*)(w + 8192 * 1024);        // 4 MB
    unsigned* bar = (unsigned*)(w + 12288 * 1024);    // 64 B

    hipMemsetAsync(bar, 0, 64, stream);
    pack_frag_kernel<<<512, 256, 0, stream>>>(W1, W1h, W1l, 8, H_, V_ * H_);
    pack_frag_kernel<<<1024, 256, 0, stream>>>(W2, W2h, W2l, 16, V_, V_ * V_);
    pack_frag_kernel<<<8192, 256, 0, stream>>>(W3, W3h, W3l, 16, V_, (H_ * D_) * V_);
    h0_kernel<<<B_, H_, 0, stream>>>(coeffs, W0, b0, hbuf);

    NcdeParams prm;
    prm.coeffs = coeffs;
    prm.W1h = W1h; prm.W1l = W1l; prm.b1 = b1; prm.g1 = g1; prm.be1 = be1;
    prm.W2h = W2h; prm.W2l = W2l; prm.b2 = b2; prm.g2 = g2; prm.be2 = be2;
    prm.W3h = W3h; prm.W3l = W3l; prm.b3 = b3;
    prm.hbuf = hbuf;
    prm.t1h = t1h; prm.t1l = t1l; prm.t2h = t2h; prm.t2l = t2l;
    prm.bar = bar;

    ncde_persistent<<<256, 512, 0, stream>>>(prm);

    hipMemcpyAsync(d_out, hbuf, (size_t)B_ * H_ * sizeof(float),
                   hipMemcpyDeviceToDevice, stream);
}